// Round 2
// baseline (297.890 us; speedup 1.0000x reference)
//
#include <hip/hip_runtime.h>
#include <math.h>

#define TT 16384            // tokens
#define HD 4096             // hidden
#define NE 64               // experts
// ---- split-K GEMM geometry ----
#define KSPLIT 8
#define HSP (HD / KSPLIT)   // 512 h per split
#define TMA 128             // tokens per A-block
#define BKA 32              // h per staged tile
#define NKTA (HSP / BKA)    // 16 k-iterations
#define NTB (TT / TMA)      // 128 token-blocks (x8 splits = 1024 blocks)
// ---- epilogue geometry (identical to validated round-1) ----
#define TM 32               // tokens per epilogue block
#define NBLK (TT / TM)      // 512 blocks

// ---- async global->LDS, 16B per lane (dest = wave-uniform base + lane*16) ----
__device__ __forceinline__ void async_copy16(const float* src, float* dst) {
  __builtin_amdgcn_global_load_lds(
      (const __attribute__((address_space(1))) void*)src,
      (__attribute__((address_space(3))) void*)dst, 16, 0, 0);
}

#define FMA4(A, HV, WV)                                       \
  A = fmaf((HV).x, (WV).x, A); A = fmaf((HV).y, (WV).y, A);   \
  A = fmaf((HV).z, (WV).z, A); A = fmaf((HV).w, (WV).w, A);

// =====================================================================
// Kernel A: split-K GEMM. 128 threads = 16 token-groups x 8 expert-groups.
// Thread tile 8 tokens x 8 experts (64 acc). LDS rows are 128B (BKA=32 f32);
// physical 16B slot p of row r holds logical h-chunk p ^ ((r>>3)&7) -> each
// wave's 8 address-groups hit 8 distinct bank-groups (conflict-free b128).
// =====================================================================
__launch_bounds__(128, 2)
__global__ void gemm_split(const float* __restrict__ X,
                           const float* __restrict__ W,
                           float* __restrict__ part) {
  __shared__ __align__(16) float sH[2][TMA * BKA];  // 2 x 16 KB
  __shared__ __align__(16) float sW[2][NE * BKA];   // 2 x 8 KB

  const int tid  = threadIdx.x;
  const int lane = tid & 63;
  const int w    = tid >> 6;        // wave 0..1
  const int tx   = tid & 7;         // expert group (8 experts, contiguous)
  const int ty   = tid >> 3;        // token group (8 tokens), 0..15
  const int tb   = blockIdx.x & (NTB - 1);
  const int kz   = blockIdx.x >> 7; // NTB == 128
  const int t0   = tb * TMA;
  const int h0   = kz * HSP;

  // ---- staging sources (pre-swizzled per-lane global addresses) ----
  const int lr = lane >> 3;         // row within 8-row chunk
  const int lp = lane & 7;          // 16B slot within 128B row
  const float* srcH[8];
  const float* srcW[4];
#pragma unroll
  for (int s = 0; s < 8; ++s) {
    const int rs  = w * 8 + s;                    // row-set 0..15 (8 rows each)
    const int key = rs & 7;
    srcH[s] = X + (size_t)(t0 + rs * 8 + lr) * HD + h0 + ((lp ^ key) << 2);
  }
#pragma unroll
  for (int s = 0; s < 4; ++s) {
    const int rs  = w * 4 + s;                    // expert row-set 0..7
    const int key = rs & 7;
    srcW[s] = W + (size_t)(rs * 8 + lr) * HD + h0 + ((lp ^ key) << 2);
  }

  auto stage = [&](int b, int kt) {
    const int o = kt * BKA;
#pragma unroll
    for (int s = 0; s < 8; ++s)
      async_copy16(srcH[s] + o, &sH[b][(w * 8 + s) * 256]);
#pragma unroll
    for (int s = 0; s < 4; ++s)
      async_copy16(srcW[s] + o, &sW[b][(w * 4 + s) * 256]);
  };

  float acc[8][8];
#pragma unroll
  for (int i = 0; i < 8; ++i)
#pragma unroll
    for (int j = 0; j < 8; ++j) acc[i][j] = 0.0f;

  const int tyk = ty & 7;

  auto compute = [&](int b) {
    const char* hb = (const char*)(&sH[b][0]) + (ty << 10);  // 8 token rows
    const char* wb = (const char*)(&sW[b][0]) + (tx << 10);  // 8 expert rows
#pragma unroll
    for (int p = 0; p < 8; ++p) {
      const int oH = (p ^ tyk) << 4;
      const int oW = (p ^ tx) << 4;
      float4 h[8], v[8];
#pragma unroll
      for (int i = 0; i < 8; ++i) h[i] = *(const float4*)(hb + (i << 7) + oH);
#pragma unroll
      for (int j = 0; j < 8; ++j) v[j] = *(const float4*)(wb + (j << 7) + oW);
#pragma unroll
      for (int i = 0; i < 8; ++i)
#pragma unroll
        for (int j = 0; j < 8; ++j) { FMA4(acc[i][j], h[i], v[j]) }
    }
  };

  int buf = 0;
  stage(0, 0);
  __syncthreads();
  for (int kt = 0; kt < NKTA; ++kt) {
    if (kt + 1 < NKTA) stage(buf ^ 1, kt + 1);
    compute(buf);
    __syncthreads();
    buf ^= 1;
  }

  // ---- write partial logits [kz][t][e] ----
  float* pb = part + (size_t)kz * (TT * NE) + (size_t)(t0 + ty * 8) * NE + tx * 8;
#pragma unroll
  for (int i = 0; i < 8; ++i) {
    *(float4*)(pb + i * NE)     = make_float4(acc[i][0], acc[i][1], acc[i][2], acc[i][3]);
    *(float4*)(pb + i * NE + 4) = make_float4(acc[i][4], acc[i][5], acc[i][6], acc[i][7]);
  }
}

// =====================================================================
// Kernel B: reduce KSPLIT partials -> logits, then the validated round-1
// epilogue (softmax / top-2 / renorm / loss partials).
// =====================================================================
__global__ void router_epilogue(const float* __restrict__ part,
                                float* __restrict__ out,
                                float* __restrict__ pP,
                                float* __restrict__ pC,
                                float* __restrict__ pZ) {
  __shared__ float psW[4][NE];
  __shared__ float cf[NE];
  __shared__ float zb[4];

  const int tid  = threadIdx.x;
  const int blk  = blockIdx.x;
  const int tx   = tid & 15;   // expert group (4 experts each)
  const int ty   = tid >> 4;   // token group (2 tokens each), 0..15
  const int wv   = tid >> 6;   // wave id 0..3
  const int lane = tid & 63;

  if (tid < NE) cf[tid] = 0.0f;

  // ---- reduce split partials into logits ----
  float lg[2][4];
#pragma unroll
  for (int i = 0; i < 2; ++i) {
    const int t = blk * TM + 2 * ty + i;
    float4 s = make_float4(0.f, 0.f, 0.f, 0.f);
#pragma unroll
    for (int k = 0; k < KSPLIT; ++k) {
      const float4 v = *(const float4*)(part + (size_t)k * (TT * NE) +
                                        (size_t)t * NE + 4 * tx);
      s.x += v.x; s.y += v.y; s.z += v.z; s.w += v.w;
    }
    lg[i][0] = s.x; lg[i][1] = s.y; lg[i][2] = s.z; lg[i][3] = s.w;
  }
  __syncthreads();   // cf init visible before atomics

  float psum[4] = {0.f, 0.f, 0.f, 0.f};
  float zc = 0.0f;
#pragma unroll
  for (int i = 0; i < 2; ++i) {
    const float l0 = lg[i][0], l1 = lg[i][1], l2 = lg[i][2], l3 = lg[i][3];
    float m = fmaxf(fmaxf(l0, l1), fmaxf(l2, l3));
    m = fmaxf(m, __shfl_xor(m, 1));
    m = fmaxf(m, __shfl_xor(m, 2));
    m = fmaxf(m, __shfl_xor(m, 4));
    m = fmaxf(m, __shfl_xor(m, 8));
    const float e0 = expf(l0 - m), e1 = expf(l1 - m);
    const float e2 = expf(l2 - m), e3 = expf(l3 - m);
    float zs = (e0 + e1) + (e2 + e3);
    zs += __shfl_xor(zs, 1);
    zs += __shfl_xor(zs, 2);
    zs += __shfl_xor(zs, 4);
    zs += __shfl_xor(zs, 8);
    const float p0 = e0 / zs, p1 = e1 / zs, p2 = e2 / zs, p3 = e3 / zs;
    psum[0] += p0; psum[1] += p1; psum[2] += p2; psum[3] += p3;

    // local top-2 among 4 experts (ascending index => ties keep lower)
    float v1 = p0, v2 = p1; int i1 = 4 * tx, i2 = 4 * tx + 1;
    if (p1 > p0) { v1 = p1; i1 = 4 * tx + 1; v2 = p0; i2 = 4 * tx; }
    if (p2 > v1) { v2 = v1; i2 = i1; v1 = p2; i1 = 4 * tx + 2; }
    else if (p2 > v2) { v2 = p2; i2 = 4 * tx + 2; }
    if (p3 > v1) { v2 = v1; i2 = i1; v1 = p3; i1 = 4 * tx + 3; }
    else if (p3 > v2) { v2 = p3; i2 = 4 * tx + 3; }

    // butterfly merge across the 16 lanes holding this token
#pragma unroll
    for (int s = 1; s <= 8; s <<= 1) {
      const float ov1 = __shfl_xor(v1, s); const int oi1 = __shfl_xor(i1, s);
      const float ov2 = __shfl_xor(v2, s); const int oi2 = __shfl_xor(i2, s);
      const bool o1 = (ov1 > v1) || (ov1 == v1 && oi1 < i1);
      if (o1) {
        const bool o2 = (ov2 > v1) || (ov2 == v1 && oi2 < i1);
        v2 = o2 ? ov2 : v1; i2 = o2 ? oi2 : i1;
        v1 = ov1; i1 = oi1;
      } else {
        const bool o2 = (ov1 > v2) || (ov1 == v2 && oi1 < i2);
        v2 = o2 ? ov1 : v2; i2 = o2 ? oi1 : i2;
      }
    }

    const float lz = m + logf(zs);
    if (tx == 0) {
      const int t = blk * TM + 2 * ty + i;
      const float den = v1 + v2 + 1e-9f;
      out[2 * t]     = v1 / den;
      out[2 * t + 1] = v2 / den;
      out[2 * TT + 2 * t]     = (float)i1;
      out[2 * TT + 2 * t + 1] = (float)i2;
      atomicAdd(&cf[i1], 1.0f);
      atomicAdd(&cf[i2], 1.0f);
      zc += lz * lz;
    }
  }

#pragma unroll
  for (int j = 0; j < 4; ++j) {
    psum[j] += __shfl_xor(psum[j], 16);
    psum[j] += __shfl_xor(psum[j], 32);
  }
  if (lane < 16) {
#pragma unroll
    for (int j = 0; j < 4; ++j) psW[wv][4 * lane + j] = psum[j];
  }
  float z = zc;
#pragma unroll
  for (int s = 1; s <= 32; s <<= 1) z += __shfl_xor(z, s);
  if (lane == 0) zb[wv] = z;
  __syncthreads();

  if (tid < NE) {
    pP[blk * NE + tid] = psW[0][tid] + psW[1][tid] + psW[2][tid] + psW[3][tid];
    pC[blk * NE + tid] = cf[tid];
  }
  if (tid == 0) pZ[blk] = zb[0] + zb[1] + zb[2] + zb[3];
}

__global__ void router_final(const float* __restrict__ pP,
                             const float* __restrict__ pC,
                             const float* __restrict__ pZ,
                             float* __restrict__ out) {
  const int e = threadIdx.x;  // 64 threads = 1 wave
  float sP = 0.f, sC = 0.f;
  for (int b = 0; b < NBLK; ++b) {
    sP += pP[b * NE + e];
    sC += pC[b * NE + e];
  }
  const float f = sC * (1.0f / (TT * 2.0f));
  const float P = sP * (1.0f / (float)TT);
  out[4 * TT + 2 + e] = f;
  float term = f * P;
#pragma unroll
  for (int s = 1; s <= 32; s <<= 1) term += __shfl_xor(term, s);
  float zs = 0.f;
  for (int b = e; b < NBLK; b += NE) zs += pZ[b];
#pragma unroll
  for (int s = 1; s <= 32; s <<= 1) zs += __shfl_xor(zs, s);
  if (e == 0) {
    out[4 * TT]     = 0.01f * ((float)NE * term);
    out[4 * TT + 1] = 0.001f * (zs / (float)TT);
  }
}

// =====================================================================
// Fallback (validated round-1 fused kernel) for small ws_size.
// =====================================================================
__launch_bounds__(256, 2)
__global__ void router_fused(const float* __restrict__ X,
                             const float* __restrict__ W,
                             float* __restrict__ out,
                             float* __restrict__ pP,
                             float* __restrict__ pC,
                             float* __restrict__ pZ) {
  __shared__ __align__(16) float sH[2][TM * 64];
  __shared__ __align__(16) float sW[2][NE * 64];
  __shared__ float psW[4][NE];
  __shared__ float cf[NE];
  __shared__ float zb[4];

  const int tid  = threadIdx.x;
  const int blk  = blockIdx.x;
  const int tx   = tid & 15;
  const int ty   = tid >> 4;
  const int wv   = tid >> 6;
  const int lane = tid & 63;

  if (tid < NE) cf[tid] = 0.0f;

  const int xoff = (tid & 15) << 4;
  const float* srcH[2];
  const float* srcW[4];
#pragma unroll
  for (int p = 0; p < 2; ++p) {
    const int r = ty + p * 16;
    const int sw = ((r >> 1) & 7) << 4;
    srcH[p] = X + (size_t)(blk * TM + r) * HD + ((xoff ^ sw) >> 2);
  }
#pragma unroll
  for (int p = 0; p < 4; ++p) {
    const int e = ty + p * 16;
    const int sw = ((e >> 2) & 7) << 4;
    srcW[p] = W + (size_t)e * HD + ((xoff ^ sw) >> 2);
  }

  auto stage = [&](int b, int kt) {
    const int o = kt * 64;
    float* dH = &sH[b][wv * 256];
    async_copy16(srcH[0] + o, dH);
    async_copy16(srcH[1] + o, dH + 1024);
    float* dW = &sW[b][wv * 256];
    async_copy16(srcW[0] + o, dW);
    async_copy16(srcW[1] + o, dW + 1024);
    async_copy16(srcW[2] + o, dW + 2048);
    async_copy16(srcW[3] + o, dW + 3072);
  };

  float acc[2][4] = {{0.f, 0.f, 0.f, 0.f}, {0.f, 0.f, 0.f, 0.f}};
  const int Hswz = (ty & 7) << 4;
  const int Wswz = (tx & 7) << 4;

  auto compute = [&](int b) {
    const char* hb = (const char*)(&sH[b][0]) + (ty << 9);
    const char* wb = (const char*)(&sW[b][0]) + (tx << 10);
#pragma unroll
    for (int h4 = 0; h4 < 16; ++h4) {
      const int oH = (h4 << 4) ^ Hswz;
      const int oW = (h4 << 4) ^ Wswz;
      const float4 h0 = *(const float4*)(hb + oH);
      const float4 h1 = *(const float4*)(hb + oH + 256);
      const float4 w0 = *(const float4*)(wb + oW);
      const float4 w1 = *(const float4*)(wb + oW + 256);
      const float4 w2 = *(const float4*)(wb + oW + 512);
      const float4 w3 = *(const float4*)(wb + oW + 768);
      FMA4(acc[0][0], h0, w0) FMA4(acc[0][1], h0, w1)
      FMA4(acc[0][2], h0, w2) FMA4(acc[0][3], h0, w3)
      FMA4(acc[1][0], h1, w0) FMA4(acc[1][1], h1, w1)
      FMA4(acc[1][2], h1, w2) FMA4(acc[1][3], h1, w3)
    }
  };

  int buf = 0;
  stage(0, 0);
  __syncthreads();
  for (int kt = 0; kt < 64; ++kt) {
    if (kt + 1 < 64) stage(buf ^ 1, kt + 1);
    compute(buf);
    __syncthreads();
    buf ^= 1;
  }

  float psum[4] = {0.f, 0.f, 0.f, 0.f};
  float zc = 0.0f;
#pragma unroll
  for (int i = 0; i < 2; ++i) {
    const float l0 = acc[i][0], l1 = acc[i][1], l2 = acc[i][2], l3 = acc[i][3];
    float m = fmaxf(fmaxf(l0, l1), fmaxf(l2, l3));
    m = fmaxf(m, __shfl_xor(m, 1));
    m = fmaxf(m, __shfl_xor(m, 2));
    m = fmaxf(m, __shfl_xor(m, 4));
    m = fmaxf(m, __shfl_xor(m, 8));
    const float e0 = expf(l0 - m), e1 = expf(l1 - m);
    const float e2 = expf(l2 - m), e3 = expf(l3 - m);
    float zs = (e0 + e1) + (e2 + e3);
    zs += __shfl_xor(zs, 1);
    zs += __shfl_xor(zs, 2);
    zs += __shfl_xor(zs, 4);
    zs += __shfl_xor(zs, 8);
    const float p0 = e0 / zs, p1 = e1 / zs, p2 = e2 / zs, p3 = e3 / zs;
    psum[0] += p0; psum[1] += p1; psum[2] += p2; psum[3] += p3;

    float v1 = p0, v2 = p1; int i1 = 4 * tx, i2 = 4 * tx + 1;
    if (p1 > p0) { v1 = p1; i1 = 4 * tx + 1; v2 = p0; i2 = 4 * tx; }
    if (p2 > v1) { v2 = v1; i2 = i1; v1 = p2; i1 = 4 * tx + 2; }
    else if (p2 > v2) { v2 = p2; i2 = 4 * tx + 2; }
    if (p3 > v1) { v2 = v1; i2 = i1; v1 = p3; i1 = 4 * tx + 3; }
    else if (p3 > v2) { v2 = p3; i2 = 4 * tx + 3; }

#pragma unroll
    for (int s = 1; s <= 8; s <<= 1) {
      const float ov1 = __shfl_xor(v1, s); const int oi1 = __shfl_xor(i1, s);
      const float ov2 = __shfl_xor(v2, s); const int oi2 = __shfl_xor(i2, s);
      const bool o1 = (ov1 > v1) || (ov1 == v1 && oi1 < i1);
      if (o1) {
        const bool o2 = (ov2 > v1) || (ov2 == v1 && oi2 < i1);
        v2 = o2 ? ov2 : v1; i2 = o2 ? oi2 : i1;
        v1 = ov1; i1 = oi1;
      } else {
        const bool o2 = (ov1 > v2) || (ov1 == v2 && oi1 < i2);
        v2 = o2 ? ov1 : v2; i2 = o2 ? oi1 : i2;
      }
    }

    const float lz = m + logf(zs);
    if (tx == 0) {
      const int t = blk * TM + 2 * ty + i;
      const float den = v1 + v2 + 1e-9f;
      out[2 * t]     = v1 / den;
      out[2 * t + 1] = v2 / den;
      out[2 * TT + 2 * t]     = (float)i1;
      out[2 * TT + 2 * t + 1] = (float)i2;
      atomicAdd(&cf[i1], 1.0f);
      atomicAdd(&cf[i2], 1.0f);
      zc += lz * lz;
    }
  }

#pragma unroll
  for (int j = 0; j < 4; ++j) {
    psum[j] += __shfl_xor(psum[j], 16);
    psum[j] += __shfl_xor(psum[j], 32);
  }
  if (lane < 16) {
#pragma unroll
    for (int j = 0; j < 4; ++j) psW[wv][4 * lane + j] = psum[j];
  }
  float z = zc;
#pragma unroll
  for (int s = 1; s <= 32; s <<= 1) z += __shfl_xor(z, s);
  if (lane == 0) zb[wv] = z;
  __syncthreads();

  if (tid < NE) {
    pP[blk * NE + tid] = psW[0][tid] + psW[1][tid] + psW[2][tid] + psW[3][tid];
    pC[blk * NE + tid] = cf[tid];
  }
  if (tid == 0) pZ[blk] = zb[0] + zb[1] + zb[2] + zb[3];
}

extern "C" void kernel_launch(void* const* d_in, const int* in_sizes, int n_in,
                              void* d_out, int out_size, void* d_ws, size_t ws_size,
                              hipStream_t stream) {
  const float* X = (const float*)d_in[0];   // [16384, 4096] f32
  const float* W = (const float*)d_in[1];   // [64, 4096] f32
  float* out = (float*)d_out;
  (void)in_sizes; (void)n_in; (void)out_size;

  const size_t PARTF = (size_t)KSPLIT * TT * NE;            // partial floats
  const size_t NEEDB = (PARTF + (size_t)NBLK * NE * 2 + NBLK) * sizeof(float);

  if (ws_size >= NEEDB) {
    float* part = (float*)d_ws;
    float* pP = part + PARTF;
    float* pC = pP + NBLK * NE;
    float* pZ = pC + NBLK * NE;
    gemm_split<<<dim3(NTB * KSPLIT), dim3(128), 0, stream>>>(X, W, part);
    router_epilogue<<<dim3(NBLK), dim3(256), 0, stream>>>(part, out, pP, pC, pZ);
    router_final<<<dim3(1), dim3(NE), 0, stream>>>(pP, pC, pZ, out);
  } else {
    float* pP = (float*)d_ws;
    float* pC = pP + NBLK * NE;
    float* pZ = pC + NBLK * NE;
    router_fused<<<dim3(NBLK), dim3(256), 0, stream>>>(X, W, out, pP, pC, pZ);
    router_final<<<dim3(1), dim3(NE), 0, stream>>>(pP, pC, pZ, out);
  }
}